// Round 4
// baseline (323.341 us; speedup 1.0000x reference)
//
#include <hip/hip_runtime.h>
#include <math.h>

#define N_RAYS    65536
#define N_SAMPLES 192
#define NERF_EPS  1e-10f

// Output layout (flat float32, reference return order):
//   rgb_map   [N,3]     offset 0            size 196608
//   density   [N,191]   offset 196608       size 12517376
//   acc_map   [N]       offset 12713984     size 65536
//   weights   [N,192]   offset 12779520     size 12582912
//   depth_map [N]       offset 25362432     size 65536

typedef float floatx4 __attribute__((ext_vector_type(4)));

// DPP control encodings (gfx9/CDNA):
//   row_shr:n  = 0x110+n   row_ror:n = 0x120+n
//   wave_shl:1 = 0x130     wave_shr:1 = 0x138
//   row_bcast15 = 0x142    row_bcast31 = 0x143
template <int CTRL, int RM, int BM>
__device__ __forceinline__ float dppf(float old_v, float v) {
    return __int_as_float(__builtin_amdgcn_update_dpp(
        __float_as_int(old_v), __float_as_int(v), CTRL, RM, BM, false));
}

__device__ __forceinline__ float readlane_f(float v, int lane) {
    return __int_as_float(__builtin_amdgcn_readlane(__float_as_int(v), lane));
}

// Exclusive product-scan across 64 lanes, pure DPP (VALU pipe, no LDS).
__device__ __forceinline__ float exclusive_prod_scan(float t) {
    float e = dppf<0x138, 0xf, 0xf>(1.0f, t);   // wave_shr:1, lane0 <- 1.0
    e *= dppf<0x111, 0xf, 0xf>(1.0f, e);        // row_shr:1
    e *= dppf<0x112, 0xf, 0xf>(1.0f, e);        // row_shr:2
    e *= dppf<0x114, 0xf, 0xf>(1.0f, e);        // row_shr:4
    e *= dppf<0x118, 0xf, 0xf>(1.0f, e);        // row_shr:8
    e *= dppf<0x142, 0xa, 0xf>(1.0f, e);        // row_bcast15 -> rows 1,3
    e *= dppf<0x143, 0xc, 0xf>(1.0f, e);        // row_bcast31 -> rows 2,3
    return e;
}

// Inclusive add-scan; lane 63 ends up with the wave total (read via readlane).
__device__ __forceinline__ float sum_to_lane63(float v) {
    v += dppf<0x111, 0xf, 0xf>(0.0f, v);
    v += dppf<0x112, 0xf, 0xf>(0.0f, v);
    v += dppf<0x114, 0xf, 0xf>(0.0f, v);
    v += dppf<0x118, 0xf, 0xf>(0.0f, v);
    v += dppf<0x142, 0xa, 0xf>(0.0f, v);
    v += dppf<0x143, 0xc, 0xf>(0.0f, v);
    return v;
}

__device__ __forceinline__ float fast_sigmoid(float x) {
    return __builtin_amdgcn_rcpf(1.0f + __expf(-x));
}

__global__ __launch_bounds__(256) void nerf_render_kernel(
    const float* __restrict__ raw,       // [N,S,4]
    const float* __restrict__ z_vals,    // [N,S]
    const float* __restrict__ rays_d,    // [N,3]
    float* __restrict__ rgb_map,         // [N,3]
    float* __restrict__ density_out,     // [N,S-1]
    float* __restrict__ acc_map,         // [N]
    float* __restrict__ weights_out,     // [N,S]
    float* __restrict__ depth_map)       // [N]
{
    const int wave = threadIdx.x >> 6;
    const int lane = threadIdx.x & 63;
    const int ray  = blockIdx.x * 4 + wave;

    const float dx = rays_d[ray * 3 + 0];
    const float dy = rays_d[ray * 3 + 1];
    const float dz = rays_d[ray * 3 + 2];
    const float dnorm = sqrtf(dx * dx + dy * dy + dz * dz);

    const floatx4* __restrict__ raw4 = (const floatx4*)raw;
    const size_t rbase = (size_t)ray * N_SAMPLES;

    // ---- all global loads upfront (MLP); raw/weights stream nontemporally ----
    const floatx4 rv0 = __builtin_nontemporal_load(&raw4[rbase + lane]);
    const floatx4 rv1 = __builtin_nontemporal_load(&raw4[rbase + 64 + lane]);
    const floatx4 rv2 = __builtin_nontemporal_load(&raw4[rbase + 128 + lane]);

    const float z0 = z_vals[rbase + lane];
    const float z1 = z_vals[rbase + 64 + lane];
    const float z2 = z_vals[rbase + 128 + lane];

    // zn = z shifted one sample: wave_shl:1 (lane i <- lane i+1),
    // lane 63 takes the next chunk's lane-0 value via readlane-broadcast old.
    const float zn0 = dppf<0x130, 0xf, 0xf>(readlane_f(z1, 0), z0);
    const float zn1 = dppf<0x130, 0xf, 0xf>(readlane_f(z2, 0), z1);
    const float zn2 = dppf<0x130, 0xf, 0xf>(0.0f, z2);  // lane 63 unused (alpha=1)

    // ---- alpha / scan operand t ----
    const float dens0 = fmaxf(rv0.w, 0.0f);
    const float dens1 = fmaxf(rv1.w, 0.0f);
    const float dens2 = fmaxf(rv2.w, 0.0f);

    const float dist0 = fabsf(zn0 - z0) * dnorm;
    const float dist1 = fabsf(zn1 - z1) * dnorm;
    const float dist2 = fabsf(zn2 - z2) * dnorm;

    const float alpha0 = 1.0f - __expf(-dens0 * dist0);
    const float alpha1 = 1.0f - __expf(-dens1 * dist1);
    const float alpha2 = (lane < 63) ? (1.0f - __expf(-dens2 * dist2)) : 1.0f;

    const float t0 = (1.0f + NERF_EPS) - alpha0;
    const float t1 = (1.0f + NERF_EPS) - alpha1;
    const float t2 = (1.0f + NERF_EPS) - alpha2;

    // ---- three independent exclusive product-scans (DPP, VALU-only) ----
    const float e0 = exclusive_prod_scan(t0);
    const float e1 = exclusive_prod_scan(t1);
    const float e2 = exclusive_prod_scan(t2);

    // chunk total products (inclusive value at lane 63, via SALU readlane)
    const float P0 = readlane_f(e0 * t0, 63);
    const float P1 = readlane_f(e1 * t1, 63);

    const float w0 = alpha0 * e0;
    const float w1 = alpha1 * (P0 * e1);
    const float w2 = alpha2 * ((P0 * P1) * e2);

    // ---- sigmoid rgb + per-lane partials ----
    const float r0 = fast_sigmoid(rv0.x), g0 = fast_sigmoid(rv0.y), b0 = fast_sigmoid(rv0.z);
    const float r1 = fast_sigmoid(rv1.x), g1 = fast_sigmoid(rv1.y), b1 = fast_sigmoid(rv1.z);
    const float r2 = fast_sigmoid(rv2.x), g2 = fast_sigmoid(rv2.y), b2 = fast_sigmoid(rv2.z);

    float rsum = w0 * r0 + w1 * r1 + w2 * r2;
    float gsum = w0 * g0 + w1 * g1 + w2 * g2;
    float bsum = w0 * b0 + w1 * b1 + w2 * b2;
    float dsum = w0 * z0 + w1 * z1 + w2 * z2;
    float asum = w0 + w1 + w2;

    // ---- streaming stores ----
    __builtin_nontemporal_store(w0, &weights_out[rbase + lane]);
    __builtin_nontemporal_store(w1, &weights_out[rbase + 64 + lane]);
    __builtin_nontemporal_store(w2, &weights_out[rbase + 128 + lane]);

    const size_t dbase = (size_t)ray * (N_SAMPLES - 1);
    __builtin_nontemporal_store(dens0, &density_out[dbase + lane]);
    __builtin_nontemporal_store(dens1, &density_out[dbase + 64 + lane]);
    if (lane < 63)
        __builtin_nontemporal_store(dens2, &density_out[dbase + 128 + lane]);

    // ---- five DPP reductions (VALU), totals read from lane 63 via SALU ----
    const float rtot = readlane_f(sum_to_lane63(rsum), 63);
    const float gtot = readlane_f(sum_to_lane63(gsum), 63);
    const float btot = readlane_f(sum_to_lane63(bsum), 63);
    const float dtot = readlane_f(sum_to_lane63(dsum), 63);
    const float atot = readlane_f(sum_to_lane63(asum), 63);

    if (lane == 0) {
        rgb_map[ray * 3 + 0] = rtot;
        rgb_map[ray * 3 + 1] = gtot;
        rgb_map[ray * 3 + 2] = btot;
        depth_map[ray] = dtot;
        acc_map[ray]   = atot;
    }
}

extern "C" void kernel_launch(void* const* d_in, const int* in_sizes, int n_in,
                              void* d_out, int out_size, void* d_ws, size_t ws_size,
                              hipStream_t stream) {
    const float* raw    = (const float*)d_in[0];
    const float* z_vals = (const float*)d_in[1];
    const float* rays_d = (const float*)d_in[2];

    float* out = (float*)d_out;
    float* rgb_map     = out;                       // 65536*3
    float* density_out = out + 196608;              // 65536*191
    float* acc_map     = out + 12713984;            // 65536
    float* weights_out = out + 12779520;            // 65536*192
    float* depth_map   = out + 25362432;            // 65536

    const int blocks = N_RAYS / 4;                  // 4 waves (rays) per block
    nerf_render_kernel<<<blocks, 256, 0, stream>>>(
        raw, z_vals, rays_d,
        rgb_map, density_out, acc_map, weights_out, depth_map);
}

// Round 5
// 322.730 us; speedup vs baseline: 1.0019x; 1.0019x over previous
//
#include <hip/hip_runtime.h>
#include <math.h>

#define N_RAYS    65536
#define N_SAMPLES 192

// Output layout (flat float32, reference return order):
//   rgb_map   [N,3]     offset 0            size 196608
//   density   [N,191]   offset 196608       size 12517376
//   acc_map   [N]       offset 12713984     size 65536
//   weights   [N,192]   offset 12779520     size 12582912
//   depth_map [N]       offset 25362432     size 65536
//
// Math note: in fp32, (1.0f + 1e-10f) == 1.0f, so the reference's scan operand
// t = (1+eps) - alpha == exp(-sigma*dist) exactly (mod rounding). We therefore
// compute transmittance in LOG space: trans_i = exp(-cumsum_excl(sigma*dist)).
// Additive scans have identity 0 => every DPP step fuses to one v_add_f32_dpp.

typedef float floatx4 __attribute__((ext_vector_type(4)));

template <int CTRL, int RM, int BM>
__device__ __forceinline__ float dpp0(float v) {
    // bound_ctrl=1 (invalid lanes read 0), old=0 -> fusable with the consumer add
    return __int_as_float(__builtin_amdgcn_update_dpp(
        0, __float_as_int(v), CTRL, RM, BM, true));
}

__device__ __forceinline__ float readlane_f(float v, int lane) {
    return __int_as_float(__builtin_amdgcn_readlane(__float_as_int(v), lane));
}

// Exclusive ADD-scan across 64 lanes: 7 fused DPP instructions.
__device__ __forceinline__ float exclusive_add_scan(float d) {
    float s = dpp0<0x138, 0xf, 0xf>(d);   // wave_shr:1, lane0 <- 0 (identity)
    s += dpp0<0x111, 0xf, 0xf>(s);        // row_shr:1
    s += dpp0<0x112, 0xf, 0xf>(s);        // row_shr:2
    s += dpp0<0x114, 0xf, 0xf>(s);        // row_shr:4
    s += dpp0<0x118, 0xf, 0xf>(s);        // row_shr:8
    s += dpp0<0x142, 0xa, 0xf>(s);        // row_bcast15 -> rows 1,3
    s += dpp0<0x143, 0xc, 0xf>(s);        // row_bcast31 -> rows 2,3
    return s;
}

// Wave-sum; total lands in lane 63. 6 fused DPP instructions.
__device__ __forceinline__ float sum_to_lane63(float v) {
    v += dpp0<0x111, 0xf, 0xf>(v);
    v += dpp0<0x112, 0xf, 0xf>(v);
    v += dpp0<0x114, 0xf, 0xf>(v);
    v += dpp0<0x118, 0xf, 0xf>(v);
    v += dpp0<0x142, 0xa, 0xf>(v);
    v += dpp0<0x143, 0xc, 0xf>(v);
    return v;
}

__device__ __forceinline__ float fast_sigmoid(float x) {
    return __builtin_amdgcn_rcpf(1.0f + __expf(-x));
}

__global__ __launch_bounds__(256) void nerf_render_kernel(
    const float* __restrict__ raw,       // [N,S,4]
    const float* __restrict__ z_vals,    // [N,S]
    const float* __restrict__ rays_d,    // [N,3]
    float* __restrict__ rgb_map,         // [N,3]
    float* __restrict__ density_out,     // [N,S-1]
    float* __restrict__ acc_map,         // [N]
    float* __restrict__ weights_out,     // [N,S]
    float* __restrict__ depth_map)       // [N]
{
    const int wave = threadIdx.x >> 6;
    const int lane = threadIdx.x & 63;
    const int ray  = blockIdx.x * 4 + wave;   // wave-uniform -> scalar loads below

    const float dx = rays_d[ray * 3 + 0];
    const float dy = rays_d[ray * 3 + 1];
    const float dz = rays_d[ray * 3 + 2];
    const float dnorm = sqrtf(dx * dx + dy * dy + dz * dz);

    const floatx4* __restrict__ raw4 = (const floatx4*)raw;
    const size_t rbase = (size_t)ray * N_SAMPLES;

    // ---- all global loads upfront (MLP); streaming data nontemporal ----
    const floatx4 rv0 = __builtin_nontemporal_load(&raw4[rbase + lane]);
    const floatx4 rv1 = __builtin_nontemporal_load(&raw4[rbase + 64 + lane]);
    const floatx4 rv2 = __builtin_nontemporal_load(&raw4[rbase + 128 + lane]);

    const float z0 = z_vals[rbase + lane];
    const float z1 = z_vals[rbase + 64 + lane];
    const float z2 = z_vals[rbase + 128 + lane];

    // zn = z shifted down one sample (wave_shl:1); lane 63 patched from the
    // next chunk's lane 0 via readlane (wave_shl leaves lane63 = 0 w/ bound_ctrl).
    float zn0 = dpp0<0x130, 0xf, 0xf>(z0);
    float zn1 = dpp0<0x130, 0xf, 0xf>(z1);
    const float zn2 = dpp0<0x130, 0xf, 0xf>(z2);   // lane 63 unused (alpha=1)
    if (lane == 63) { zn0 = readlane_f(z1, 0); zn1 = readlane_f(z2, 0); }

    // ---- optical depth per sample: d = relu(sigma) * dist ----
    const float dens0 = fmaxf(rv0.w, 0.0f);
    const float dens1 = fmaxf(rv1.w, 0.0f);
    const float dens2 = fmaxf(rv2.w, 0.0f);

    const float d0 = dens0 * (fabsf(zn0 - z0) * dnorm);
    const float d1 = dens1 * (fabsf(zn1 - z1) * dnorm);
    const float d2 = dens2 * (fabsf(zn2 - z2) * dnorm);   // lane63 value unused

    // ---- three independent exclusive ADD-scans (fully fused DPP) ----
    const float S0 = exclusive_add_scan(d0);
    const float S1 = exclusive_add_scan(d1);
    const float S2 = exclusive_add_scan(d2);

    // cross-chunk carries (inclusive total at lane 63)
    const float C1 = readlane_f(S0 + d0, 63);
    const float C2 = C1 + readlane_f(S1 + d1, 63);

    // transmittance and weights: w = (1 - exp(-d)) * exp(-(S + carry))
    const float tr0 = __expf(-S0);
    const float tr1 = __expf(-(S1 + C1));
    const float tr2 = __expf(-(S2 + C2));

    const float a0 = 1.0f - __expf(-d0);
    const float a1 = 1.0f - __expf(-d1);
    const float a2 = (lane < 63) ? (1.0f - __expf(-d2)) : 1.0f;

    const float w0 = a0 * tr0;
    const float w1 = a1 * tr1;
    const float w2 = a2 * tr2;

    // ---- sigmoid rgb + per-lane partials ----
    const float r0 = fast_sigmoid(rv0.x), g0 = fast_sigmoid(rv0.y), b0 = fast_sigmoid(rv0.z);
    const float r1 = fast_sigmoid(rv1.x), g1 = fast_sigmoid(rv1.y), b1 = fast_sigmoid(rv1.z);
    const float r2 = fast_sigmoid(rv2.x), g2 = fast_sigmoid(rv2.y), b2 = fast_sigmoid(rv2.z);

    float rsum = w0 * r0 + w1 * r1 + w2 * r2;
    float gsum = w0 * g0 + w1 * g1 + w2 * g2;
    float bsum = w0 * b0 + w1 * b1 + w2 * b2;
    float dsum = w0 * z0 + w1 * z1 + w2 * z2;
    float asum = w0 + w1 + w2;

    // ---- streaming stores ----
    __builtin_nontemporal_store(w0, &weights_out[rbase + lane]);
    __builtin_nontemporal_store(w1, &weights_out[rbase + 64 + lane]);
    __builtin_nontemporal_store(w2, &weights_out[rbase + 128 + lane]);

    const size_t dbase = (size_t)ray * (N_SAMPLES - 1);
    __builtin_nontemporal_store(dens0, &density_out[dbase + lane]);
    __builtin_nontemporal_store(dens1, &density_out[dbase + 64 + lane]);
    if (lane < 63)
        __builtin_nontemporal_store(dens2, &density_out[dbase + 128 + lane]);

    // ---- five fused-DPP reductions, totals read from lane 63 (SALU) ----
    const float rtot = readlane_f(sum_to_lane63(rsum), 63);
    const float gtot = readlane_f(sum_to_lane63(gsum), 63);
    const float btot = readlane_f(sum_to_lane63(bsum), 63);
    const float dtot = readlane_f(sum_to_lane63(dsum), 63);
    const float atot = readlane_f(sum_to_lane63(asum), 63);

    if (lane == 0) {
        rgb_map[ray * 3 + 0] = rtot;
        rgb_map[ray * 3 + 1] = gtot;
        rgb_map[ray * 3 + 2] = btot;
        depth_map[ray] = dtot;
        acc_map[ray]   = atot;
    }
}

extern "C" void kernel_launch(void* const* d_in, const int* in_sizes, int n_in,
                              void* d_out, int out_size, void* d_ws, size_t ws_size,
                              hipStream_t stream) {
    const float* raw    = (const float*)d_in[0];
    const float* z_vals = (const float*)d_in[1];
    const float* rays_d = (const float*)d_in[2];

    float* out = (float*)d_out;
    float* rgb_map     = out;                       // 65536*3
    float* density_out = out + 196608;              // 65536*191
    float* acc_map     = out + 12713984;            // 65536
    float* weights_out = out + 12779520;            // 65536*192
    float* depth_map   = out + 25362432;            // 65536

    const int blocks = N_RAYS / 4;                  // 4 waves (rays) per block
    nerf_render_kernel<<<blocks, 256, 0, stream>>>(
        raw, z_vals, rays_d,
        rgb_map, density_out, acc_map, weights_out, depth_map);
}